// Round 7
// baseline (185.530 us; speedup 1.0000x reference)
//
#include <hip/hip_runtime.h>

// Varlen causal GQA prefill attention, B=4 S=2048 Hq=16 Hkv=4 D=128 (fp32 io).
// R7: R2's per-wave structure (best measured) + occupancy-based latency hiding:
// single-buffered K/V (32KB LDS) -> ~4-5 blocks/CU co-resident (vs 2), TLP
// replaces intra-block prefetch (m114). Heavy-first 1024-block queue for
// dynamic load balance (no placement assumptions — R6 lesson).
// Keeps: 32x32x16 MFMA, swapped QK^T, exp2-domain softmax, in-register P via
// cvt_pk+permlane32_swap, defer-max, swizzled K/V images, tree reductions.

typedef __attribute__((ext_vector_type(8))) short bs8;       // 8 bf16 (4 VGPR)
typedef __attribute__((ext_vector_type(16))) float f16x;     // 32x32 acc
typedef __attribute__((ext_vector_type(4))) unsigned int u32x4;
typedef __attribute__((ext_vector_type(4))) unsigned short u16x4;
typedef unsigned short u16;
typedef unsigned int u32;

#define B_ 4
#define S_ 2048
#define HQ_ 16
#define HKV_ 4
#define NQT 16        // q-tiles of 128
#define NKT_TOT 32    // kv-tiles of 64
#define TILE_ELEMS 8192  // 64x128 bf16 = 16KB

__device__ __forceinline__ u16 f2bf(float f) {  // fp32 -> bf16 RNE
  u32 u = __float_as_uint(f);
  u += 0x7fffu + ((u >> 16) & 1u);
  return (u16)(u >> 16);
}

// ---- pre-pass 1: K -> bf16 tile images, elem(kv,d) = kv*128 + (d ^ 8*(kv&15))
__global__ void pack_k(const float* __restrict__ k, u16* __restrict__ kp) {
  int g = blockIdx.x * 256 + threadIdx.x;
  int row = g >> 7;
  int col = (g & 127) << 2;
  int h = col >> 7, d0 = col & 127;
  int b = row >> 11, s = row & 2047;
  int kt = s >> 6, kv = s & 63;
  float4 vv = *(const float4*)(k + (size_t)row * 512 + col);
  int ti = (b * HKV_ + h) * NKT_TOT + kt;
  int e = kv * 128 + (d0 ^ (8 * (kv & 15)));
  u16x4 o;
  o.x = f2bf(vv.x); o.y = f2bf(vv.y); o.z = f2bf(vv.z); o.w = f2bf(vv.w);
  *(u16x4*)(kp + (size_t)ti * TILE_ELEMS + e) = o;
}

// ---- pre-pass 2: V -> bf16 V^T images, elem(d,kv) =
//        (d>>1)*128 + (d&1)*64 + (kv ^ 8*((d>>1)&7)); built in LDS, copied linear.
__global__ void pack_v(const float* __restrict__ v, u16* __restrict__ vp) {
  __shared__ u16 img[TILE_ELEMS];
  int ti = blockIdx.x;                 // (b*HKV+h)*32 + kt
  int kt = ti & 31;
  int bh = ti >> 5;
  int h = bh & 3, b = bh >> 2;
  int t = threadIdx.x;
#pragma unroll
  for (int p = 0; p < 8; ++p) {
    int t2 = p * 256 + t;
    int kvr = t2 >> 5;
    int d0 = (t2 & 31) << 2;
    float4 vv = *(const float4*)(v + (size_t)(b * S_ + kt * 64 + kvr) * 512 + h * 128 + d0);
    float a[4] = {vv.x, vv.y, vv.z, vv.w};
#pragma unroll
    for (int j = 0; j < 4; ++j) {
      int d = d0 + j;
      img[(d >> 1) * 128 + (d & 1) * 64 + (kvr ^ (8 * ((d >> 1) & 7)))] = f2bf(a[j]);
    }
  }
  __syncthreads();
#pragma unroll
  for (int p = 0; p < 4; ++p) {
    int e0 = (p * 256 + t) * 8;
    *(bs8*)(vp + (size_t)ti * TILE_ELEMS + e0) = *(const bs8*)&img[e0];
  }
}

// ---- main flash attention ---------------------------------------------------
__device__ __forceinline__ void gl2lds(const u16* g, u16* l) {
  __builtin_amdgcn_global_load_lds((const __attribute__((address_space(1))) void*)g,
                                   (__attribute__((address_space(3))) void*)l,
                                   16, 0, 0);
}

// NOTE: on this toolchain __launch_bounds__ 2nd arg acts as BLOCKS/CU
// (R3 evidence: (512,4) -> 64-VGPR cap -> spill). (256,4) -> 16 waves/CU,
// 128-VGPR cap; kernel sits at ~90 VGPR so no spill risk.
__global__ __launch_bounds__(256, 4) void attn_fwd(
    const float* __restrict__ q, const u16* __restrict__ kp,
    const u16* __restrict__ vp, float* __restrict__ out) {
  __shared__ u16 Ks[TILE_ELEMS];       // single-buffered: 32KB total LDS
  __shared__ u16 Vs[TILE_ELEMS];

  const int bx = blockIdx.x;
  const int qt = (NQT - 1) - (bx >> 6);   // heavy q-tiles first (queue balance)
  const int bh = bx & 63;
  const int b = bh >> 4, hq = bh & 15, hkv = hq >> 2;
  const int w = threadIdx.x >> 6, lane = threadIdx.x & 63;
  const int l31 = lane & 31, hi = lane >> 5;
  const int q0 = qt * 128;
  const float scale2 = 0.08838834764831845f * 1.4426950408889634f;  // /sqrt(D)*log2(e)

  // Q B-frags in registers: qf[ki] = Q[q=l31][ki*16 + hi*8 + 0..7] * scale2
  bs8 qf[8];
  {
    int row = b * S_ + q0 + w * 32 + l31;
    const float* qrow = q + (size_t)row * 2048 + hq * 128;
#pragma unroll
    for (int ki = 0; ki < 8; ++ki) {
      const float* p0 = qrow + ki * 16 + hi * 8;
      float4 a = *(const float4*)p0;
      float4 c = *(const float4*)(p0 + 4);
      bs8 f;
      f[0] = (short)f2bf(a.x * scale2); f[1] = (short)f2bf(a.y * scale2);
      f[2] = (short)f2bf(a.z * scale2); f[3] = (short)f2bf(a.w * scale2);
      f[4] = (short)f2bf(c.x * scale2); f[5] = (short)f2bf(c.y * scale2);
      f[6] = (short)f2bf(c.z * scale2); f[7] = (short)f2bf(c.w * scale2);
      qf[ki] = f;
    }
  }

  f16x O[4];
#pragma unroll
  for (int dt = 0; dt < 4; ++dt)
#pragma unroll
    for (int e = 0; e < 16; ++e) O[dt][e] = 0.f;
  float m_run = -1e30f, l_run = 0.f;   // log2-domain

  const size_t tbase = (size_t)((b * HKV_ + hkv) * NKT_TOT) * TILE_ELEMS;
  const u16* kbase = kp + tbase;
  const u16* vbase = vp + tbase;
  const int nkt = 2 * qt + 2;
  const int myrowmax = q0 + w * 32 + 31;
  const int qpos = q0 + w * 32 + l31;

  const int swzk = 8 * (l31 & 15);
  const int swzv = 8 * ((l31 >> 1) & 7);
  const int vrowbase = (l31 >> 1) * 128 + (l31 & 1) * 64;

  for (int t = 0; t < nkt; ++t) {
    __syncthreads();  // previous tile fully consumed before overwrite
    {
      const u16* kg = kbase + (size_t)t * TILE_ELEMS;
      const u16* vg = vbase + (size_t)t * TILE_ELEMS;
#pragma unroll
      for (int j = 0; j < 4; ++j) {
        int c = w * 4 + j;
        gl2lds(kg + c * 512 + lane * 8, &Ks[c * 512]);
        gl2lds(vg + c * 512 + lane * 8, &Vs[c * 512]);
      }
    }
    asm volatile("s_waitcnt vmcnt(0)" ::: "memory");
    __syncthreads();

    if (t * 64 <= myrowmax) {  // wave-level causal tile skip (no barriers inside)
      // ---- QK^T swapped: S[kv][q], col=lane&31=q ----
      f16x Sa[2];
#pragma unroll
      for (int kb = 0; kb < 2; ++kb)
#pragma unroll
        for (int e = 0; e < 16; ++e) Sa[kb][e] = 0.f;

      __builtin_amdgcn_s_setprio(1);
#pragma unroll
      for (int ki = 0; ki < 8; ++ki) {
        int koff = (ki * 16 + hi * 8) ^ swzk;
#pragma unroll
        for (int kb = 0; kb < 2; ++kb) {
          bs8 kf = *(const bs8*)&Ks[(kb * 32 + l31) * 128 + koff];
          Sa[kb] = __builtin_amdgcn_mfma_f32_32x32x16_bf16(kf, qf[ki], Sa[kb], 0, 0, 0);
        }
      }
      __builtin_amdgcn_s_setprio(0);

      // ---- causal mask (only the last two tiles straddle the diagonal) ----
      if (t >= 2 * qt) {
#pragma unroll
        for (int kb = 0; kb < 2; ++kb)
#pragma unroll
          for (int r = 0; r < 16; ++r) {
            int kvpos = t * 64 + kb * 32 + (r & 3) + 8 * (r >> 2) + 4 * hi;
            if (kvpos > qpos) Sa[kb][r] = -1e30f;
          }
      }

      // ---- pmax: pairwise tree (short dep chain) ----
      float tm[8];
#pragma unroll
      for (int r = 0; r < 8; ++r)
        tm[r] = fmaxf(fmaxf(Sa[0][r], Sa[0][r + 8]), fmaxf(Sa[1][r], Sa[1][r + 8]));
#pragma unroll
      for (int s = 4; s > 0; s >>= 1)
#pragma unroll
        for (int r = 0; r < s; ++r) tm[r] = fmaxf(tm[r], tm[r + s]);
      float pmax = fmaxf(tm[0], __shfl_xor(tm[0], 32, 64));

      if (__any(pmax > m_run + 8.0f)) {  // defer-max
        float mnew = fmaxf(m_run, pmax);
        float alpha = exp2f(m_run - mnew);
        m_run = mnew;
        l_run *= alpha;
#pragma unroll
        for (int r = 0; r < 16; ++r) {
          float ar = __shfl(alpha, (r & 3) + 8 * (r >> 2) + 4 * hi, 64);
#pragma unroll
          for (int dt = 0; dt < 4; ++dt) O[dt][r] *= ar;
        }
      }

      // ---- exp2 + psum tree ----
#pragma unroll
      for (int kb = 0; kb < 2; ++kb)
#pragma unroll
        for (int r = 0; r < 16; ++r) Sa[kb][r] = exp2f(Sa[kb][r] - m_run);
      float ts[8];
#pragma unroll
      for (int r = 0; r < 8; ++r)
        ts[r] = (Sa[0][r] + Sa[0][r + 8]) + (Sa[1][r] + Sa[1][r + 8]);
#pragma unroll
      for (int s = 4; s > 0; s >>= 1)
#pragma unroll
        for (int r = 0; r < s; ++r) ts[r] += ts[r + s];
      l_run += ts[0];

      // ---- P f32 -> bf16 A-frags: cvt_pk + permlane32_swap (T12) ----
      bs8 pf[2][2];
#pragma unroll
      for (int kb = 0; kb < 2; ++kb) {
        u32 pk_[8];
#pragma unroll
        for (int j = 0; j < 8; ++j) {
          float lo = Sa[kb][2 * j], hif = Sa[kb][2 * j + 1];
          asm("v_cvt_pk_bf16_f32 %0, %1, %2" : "=v"(pk_[j]) : "v"(lo), "v"(hif));
        }
#pragma unroll
        for (int ks = 0; ks < 2; ++ks) {
          auto s0 = __builtin_amdgcn_permlane32_swap((int)pk_[4 * ks], (int)pk_[4 * ks + 2], false, false);
          auto s1 = __builtin_amdgcn_permlane32_swap((int)pk_[4 * ks + 1], (int)pk_[4 * ks + 3], false, false);
          u32x4 fw;
          fw[0] = (u32)s0[0]; fw[1] = (u32)s1[0]; fw[2] = (u32)s0[1]; fw[3] = (u32)s1[1];
          pf[kb][ks] = __builtin_bit_cast(bs8, fw);
        }
      }

      // ---- PV: O[q][d] += P[q][kv] * V[kv][d], col=lane&31=d ----
      __builtin_amdgcn_s_setprio(1);
#pragma unroll
      for (int dt = 0; dt < 4; ++dt) {
#pragma unroll
        for (int kb = 0; kb < 2; ++kb)
#pragma unroll
          for (int ks = 0; ks < 2; ++ks) {
            int kvoff = (kb * 32 + ks * 16 + hi * 8) ^ swzv;
            bs8 vb = *(const bs8*)&Vs[dt * 2048 + vrowbase + kvoff];
            O[dt] = __builtin_amdgcn_mfma_f32_32x32x16_bf16(pf[kb][ks], vb, O[dt], 0, 0, 0);
          }
      }
      __builtin_amdgcn_s_setprio(0);
    }
  }

  // ---- epilogue: combine l halves, normalize, coalesced store ----
  float lt = l_run + __shfl_xor(l_run, 32, 64);
  float inv = 1.0f / lt;
  const int orow0 = b * S_ + q0 + w * 32;
#pragma unroll
  for (int r = 0; r < 16; ++r) {
    int qr = (r & 3) + 8 * (r >> 2) + 4 * hi;
    float li = __shfl(inv, qr, 64);
    float* op = out + (size_t)(orow0 + qr) * 2048 + hq * 128 + l31;
#pragma unroll
    for (int dt = 0; dt < 4; ++dt) op[dt * 32] = O[dt][r] * li;
  }
}

extern "C" void kernel_launch(void* const* d_in, const int* in_sizes, int n_in,
                              void* d_out, int out_size, void* d_ws, size_t ws_size,
                              hipStream_t stream) {
  const float* q = (const float*)d_in[0];
  const float* k = (const float*)d_in[1];
  const float* v = (const float*)d_in[2];
  float* out = (float*)d_out;
  u16* kp = (u16*)d_ws;                                       // 8 MB K images
  u16* vp = kp + (size_t)B_ * HKV_ * NKT_TOT * TILE_ELEMS;    // 8 MB V^T images

  pack_k<<<(B_ * S_ * 512 / 4) / 256, 256, 0, stream>>>(k, kp);
  pack_v<<<B_ * HKV_ * NKT_TOT, 256, 0, stream>>>(v, vp);
  attn_fwd<<<B_ * HQ_ * NQT, 256, 0, stream>>>(q, kp, vp, out);
}

// Round 8
// 120.351 us; speedup vs baseline: 1.5416x; 1.5416x over previous
//
#include <hip/hip_runtime.h>

// Varlen causal GQA prefill attention, B=4 S=2048 Hq=16 Hkv=4 D=128 (fp32 io).
// R8 = R7 with the register cap fixed. Toolchain rule (R3+R7 evidence):
// __launch_bounds__(B, w) caps VGPR at 256/w regardless of B. w=4 -> 64-VGPR
// cap -> spill (R7: WRITE_SIZE 113MB, FETCH 344MB). w=2 -> 128 cap, fits ~120.
// Structure: R2's serial per-wave compute, single-buffered K/V (32KB LDS) ->
// 4 blocks/CU co-resident (16 waves/CU); inter-block TLP hides the per-block
// stage->drain window (m114). Heavy-first 1024-block queue for load balance.
// Keeps: 32x32x16 MFMA, swapped QK^T, exp2-domain softmax, in-register P via
// cvt_pk+permlane32_swap, defer-max, swizzled K/V images, tree reductions.

typedef __attribute__((ext_vector_type(8))) short bs8;       // 8 bf16 (4 VGPR)
typedef __attribute__((ext_vector_type(16))) float f16x;     // 32x32 acc
typedef __attribute__((ext_vector_type(4))) unsigned int u32x4;
typedef __attribute__((ext_vector_type(4))) unsigned short u16x4;
typedef unsigned short u16;
typedef unsigned int u32;

#define B_ 4
#define S_ 2048
#define HQ_ 16
#define HKV_ 4
#define NQT 16        // q-tiles of 128
#define NKT_TOT 32    // kv-tiles of 64
#define TILE_ELEMS 8192  // 64x128 bf16 = 16KB

__device__ __forceinline__ u16 f2bf(float f) {  // fp32 -> bf16 RNE
  u32 u = __float_as_uint(f);
  u += 0x7fffu + ((u >> 16) & 1u);
  return (u16)(u >> 16);
}

// ---- pre-pass 1: K -> bf16 tile images, elem(kv,d) = kv*128 + (d ^ 8*(kv&15))
__global__ void pack_k(const float* __restrict__ k, u16* __restrict__ kp) {
  int g = blockIdx.x * 256 + threadIdx.x;
  int row = g >> 7;
  int col = (g & 127) << 2;
  int h = col >> 7, d0 = col & 127;
  int b = row >> 11, s = row & 2047;
  int kt = s >> 6, kv = s & 63;
  float4 vv = *(const float4*)(k + (size_t)row * 512 + col);
  int ti = (b * HKV_ + h) * NKT_TOT + kt;
  int e = kv * 128 + (d0 ^ (8 * (kv & 15)));
  u16x4 o;
  o.x = f2bf(vv.x); o.y = f2bf(vv.y); o.z = f2bf(vv.z); o.w = f2bf(vv.w);
  *(u16x4*)(kp + (size_t)ti * TILE_ELEMS + e) = o;
}

// ---- pre-pass 2: V -> bf16 V^T images, elem(d,kv) =
//        (d>>1)*128 + (d&1)*64 + (kv ^ 8*((d>>1)&7)); built in LDS, copied linear.
__global__ void pack_v(const float* __restrict__ v, u16* __restrict__ vp) {
  __shared__ u16 img[TILE_ELEMS];
  int ti = blockIdx.x;                 // (b*HKV+h)*32 + kt
  int kt = ti & 31;
  int bh = ti >> 5;
  int h = bh & 3, b = bh >> 2;
  int t = threadIdx.x;
#pragma unroll
  for (int p = 0; p < 8; ++p) {
    int t2 = p * 256 + t;
    int kvr = t2 >> 5;
    int d0 = (t2 & 31) << 2;
    float4 vv = *(const float4*)(v + (size_t)(b * S_ + kt * 64 + kvr) * 512 + h * 128 + d0);
    float a[4] = {vv.x, vv.y, vv.z, vv.w};
#pragma unroll
    for (int j = 0; j < 4; ++j) {
      int d = d0 + j;
      img[(d >> 1) * 128 + (d & 1) * 64 + (kvr ^ (8 * ((d >> 1) & 7)))] = f2bf(a[j]);
    }
  }
  __syncthreads();
#pragma unroll
  for (int p = 0; p < 4; ++p) {
    int e0 = (p * 256 + t) * 8;
    *(bs8*)(vp + (size_t)ti * TILE_ELEMS + e0) = *(const bs8*)&img[e0];
  }
}

// ---- main flash attention ---------------------------------------------------
__device__ __forceinline__ void gl2lds(const u16* g, u16* l) {
  __builtin_amdgcn_global_load_lds((const __attribute__((address_space(1))) void*)g,
                                   (__attribute__((address_space(3))) void*)l,
                                   16, 0, 0);
}

// __launch_bounds__ rule on this toolchain: VGPR cap = 256 / (2nd arg).
// (·,2) -> 128-VGPR cap; kernel compiles to ~120 VGPR -> 4 waves/SIMD.
__global__ __launch_bounds__(256, 2) void attn_fwd(
    const float* __restrict__ q, const u16* __restrict__ kp,
    const u16* __restrict__ vp, float* __restrict__ out) {
  __shared__ u16 Ks[TILE_ELEMS];       // single-buffered: 32KB total LDS
  __shared__ u16 Vs[TILE_ELEMS];

  const int bx = blockIdx.x;
  const int qt = (NQT - 1) - (bx >> 6);   // heavy q-tiles first (queue balance)
  const int bh = bx & 63;
  const int b = bh >> 4, hq = bh & 15, hkv = hq >> 2;
  const int w = threadIdx.x >> 6, lane = threadIdx.x & 63;
  const int l31 = lane & 31, hi = lane >> 5;
  const int q0 = qt * 128;
  const float scale2 = 0.08838834764831845f * 1.4426950408889634f;  // /sqrt(D)*log2(e)

  // Q B-frags in registers: qf[ki] = Q[q=l31][ki*16 + hi*8 + 0..7] * scale2
  bs8 qf[8];
  {
    int row = b * S_ + q0 + w * 32 + l31;
    const float* qrow = q + (size_t)row * 2048 + hq * 128;
#pragma unroll
    for (int ki = 0; ki < 8; ++ki) {
      const float* p0 = qrow + ki * 16 + hi * 8;
      float4 a = *(const float4*)p0;
      float4 c = *(const float4*)(p0 + 4);
      bs8 f;
      f[0] = (short)f2bf(a.x * scale2); f[1] = (short)f2bf(a.y * scale2);
      f[2] = (short)f2bf(a.z * scale2); f[3] = (short)f2bf(a.w * scale2);
      f[4] = (short)f2bf(c.x * scale2); f[5] = (short)f2bf(c.y * scale2);
      f[6] = (short)f2bf(c.z * scale2); f[7] = (short)f2bf(c.w * scale2);
      qf[ki] = f;
    }
  }

  f16x O[4];
#pragma unroll
  for (int dt = 0; dt < 4; ++dt)
#pragma unroll
    for (int e = 0; e < 16; ++e) O[dt][e] = 0.f;
  float m_run = -1e30f, l_run = 0.f;   // log2-domain

  const size_t tbase = (size_t)((b * HKV_ + hkv) * NKT_TOT) * TILE_ELEMS;
  const u16* kbase = kp + tbase;
  const u16* vbase = vp + tbase;
  const int nkt = 2 * qt + 2;
  const int myrowmax = q0 + w * 32 + 31;
  const int qpos = q0 + w * 32 + l31;

  const int swzk = 8 * (l31 & 15);
  const int swzv = 8 * ((l31 >> 1) & 7);
  const int vrowbase = (l31 >> 1) * 128 + (l31 & 1) * 64;

  for (int t = 0; t < nkt; ++t) {
    __syncthreads();  // previous tile fully consumed before overwrite
    {
      const u16* kg = kbase + (size_t)t * TILE_ELEMS;
      const u16* vg = vbase + (size_t)t * TILE_ELEMS;
#pragma unroll
      for (int j = 0; j < 4; ++j) {
        int c = w * 4 + j;
        gl2lds(kg + c * 512 + lane * 8, &Ks[c * 512]);
        gl2lds(vg + c * 512 + lane * 8, &Vs[c * 512]);
      }
    }
    asm volatile("s_waitcnt vmcnt(0)" ::: "memory");
    __syncthreads();

    if (t * 64 <= myrowmax) {  // wave-level causal tile skip (no barriers inside)
      // ---- QK^T swapped: S[kv][q], col=lane&31=q ----
      f16x Sa[2];
#pragma unroll
      for (int kb = 0; kb < 2; ++kb)
#pragma unroll
        for (int e = 0; e < 16; ++e) Sa[kb][e] = 0.f;

      __builtin_amdgcn_s_setprio(1);
#pragma unroll
      for (int ki = 0; ki < 8; ++ki) {
        int koff = (ki * 16 + hi * 8) ^ swzk;
#pragma unroll
        for (int kb = 0; kb < 2; ++kb) {
          bs8 kf = *(const bs8*)&Ks[(kb * 32 + l31) * 128 + koff];
          Sa[kb] = __builtin_amdgcn_mfma_f32_32x32x16_bf16(kf, qf[ki], Sa[kb], 0, 0, 0);
        }
      }
      __builtin_amdgcn_s_setprio(0);

      // ---- causal mask (only the last two tiles straddle the diagonal) ----
      if (t >= 2 * qt) {
#pragma unroll
        for (int kb = 0; kb < 2; ++kb)
#pragma unroll
          for (int r = 0; r < 16; ++r) {
            int kvpos = t * 64 + kb * 32 + (r & 3) + 8 * (r >> 2) + 4 * hi;
            if (kvpos > qpos) Sa[kb][r] = -1e30f;
          }
      }

      // ---- pmax: pairwise tree (short dep chain) ----
      float tm[8];
#pragma unroll
      for (int r = 0; r < 8; ++r)
        tm[r] = fmaxf(fmaxf(Sa[0][r], Sa[0][r + 8]), fmaxf(Sa[1][r], Sa[1][r + 8]));
#pragma unroll
      for (int s = 4; s > 0; s >>= 1)
#pragma unroll
        for (int r = 0; r < s; ++r) tm[r] = fmaxf(tm[r], tm[r + s]);
      float pmax = fmaxf(tm[0], __shfl_xor(tm[0], 32, 64));

      if (__any(pmax > m_run + 8.0f)) {  // defer-max
        float mnew = fmaxf(m_run, pmax);
        float alpha = exp2f(m_run - mnew);
        m_run = mnew;
        l_run *= alpha;
#pragma unroll
        for (int r = 0; r < 16; ++r) {
          float ar = __shfl(alpha, (r & 3) + 8 * (r >> 2) + 4 * hi, 64);
#pragma unroll
          for (int dt = 0; dt < 4; ++dt) O[dt][r] *= ar;
        }
      }

      // ---- exp2 + psum tree ----
#pragma unroll
      for (int kb = 0; kb < 2; ++kb)
#pragma unroll
        for (int r = 0; r < 16; ++r) Sa[kb][r] = exp2f(Sa[kb][r] - m_run);
      float ts[8];
#pragma unroll
      for (int r = 0; r < 8; ++r)
        ts[r] = (Sa[0][r] + Sa[0][r + 8]) + (Sa[1][r] + Sa[1][r + 8]);
#pragma unroll
      for (int s = 4; s > 0; s >>= 1)
#pragma unroll
        for (int r = 0; r < s; ++r) ts[r] += ts[r + s];
      l_run += ts[0];

      // ---- P f32 -> bf16 A-frags: cvt_pk + permlane32_swap (T12) ----
      bs8 pf[2][2];
#pragma unroll
      for (int kb = 0; kb < 2; ++kb) {
        u32 pk_[8];
#pragma unroll
        for (int j = 0; j < 8; ++j) {
          float lo = Sa[kb][2 * j], hif = Sa[kb][2 * j + 1];
          asm("v_cvt_pk_bf16_f32 %0, %1, %2" : "=v"(pk_[j]) : "v"(lo), "v"(hif));
        }
#pragma unroll
        for (int ks = 0; ks < 2; ++ks) {
          auto s0 = __builtin_amdgcn_permlane32_swap((int)pk_[4 * ks], (int)pk_[4 * ks + 2], false, false);
          auto s1 = __builtin_amdgcn_permlane32_swap((int)pk_[4 * ks + 1], (int)pk_[4 * ks + 3], false, false);
          u32x4 fw;
          fw[0] = (u32)s0[0]; fw[1] = (u32)s1[0]; fw[2] = (u32)s0[1]; fw[3] = (u32)s1[1];
          pf[kb][ks] = __builtin_bit_cast(bs8, fw);
        }
      }

      // ---- PV: O[q][d] += P[q][kv] * V[kv][d], col=lane&31=d ----
      __builtin_amdgcn_s_setprio(1);
#pragma unroll
      for (int dt = 0; dt < 4; ++dt) {
#pragma unroll
        for (int kb = 0; kb < 2; ++kb)
#pragma unroll
          for (int ks = 0; ks < 2; ++ks) {
            int kvoff = (kb * 32 + ks * 16 + hi * 8) ^ swzv;
            bs8 vb = *(const bs8*)&Vs[dt * 2048 + vrowbase + kvoff];
            O[dt] = __builtin_amdgcn_mfma_f32_32x32x16_bf16(pf[kb][ks], vb, O[dt], 0, 0, 0);
          }
      }
      __builtin_amdgcn_s_setprio(0);
    }
  }

  // ---- epilogue: combine l halves, normalize, coalesced store ----
  float lt = l_run + __shfl_xor(l_run, 32, 64);
  float inv = 1.0f / lt;
  const int orow0 = b * S_ + q0 + w * 32;
#pragma unroll
  for (int r = 0; r < 16; ++r) {
    int qr = (r & 3) + 8 * (r >> 2) + 4 * hi;
    float li = __shfl(inv, qr, 64);
    float* op = out + (size_t)(orow0 + qr) * 2048 + hq * 128 + l31;
#pragma unroll
    for (int dt = 0; dt < 4; ++dt) op[dt * 32] = O[dt][r] * li;
  }
}

extern "C" void kernel_launch(void* const* d_in, const int* in_sizes, int n_in,
                              void* d_out, int out_size, void* d_ws, size_t ws_size,
                              hipStream_t stream) {
  const float* q = (const float*)d_in[0];
  const float* k = (const float*)d_in[1];
  const float* v = (const float*)d_in[2];
  float* out = (float*)d_out;
  u16* kp = (u16*)d_ws;                                       // 8 MB K images
  u16* vp = kp + (size_t)B_ * HKV_ * NKT_TOT * TILE_ELEMS;    // 8 MB V^T images

  pack_k<<<(B_ * S_ * 512 / 4) / 256, 256, 0, stream>>>(k, kp);
  pack_v<<<B_ * HKV_ * NKT_TOT, 256, 0, stream>>>(v, vp);
  attn_fwd<<<B_ * HQ_ * NQT, 256, 0, stream>>>(q, kp, vp, out);
}